// Round 1
// baseline (26.828 us; speedup 1.0000x reference)
//
#include <hip/hip_runtime.h>
#include <hip/hip_bf16.h>
#include <math.h>

// Problem constants (from setup_inputs): B=1, C=256, H=W=50, N=256 boxes, OUT=7
#define RC   256
#define RH   50
#define RW   50
#define RN   256
#define ROUT 7

__global__ void __launch_bounds__(256)
roi_pool_kernel(const float* __restrict__ feat,
                const float* __restrict__ boxes,
                const int* __restrict__ image_size_p,
                float* __restrict__ out) {
    const int total = RN * RC * ROUT * ROUT;
    int idx = blockIdx.x * blockDim.x + threadIdx.x;
    if (idx >= total) return;

    int kx = idx % ROUT;
    int ky = (idx / ROUT) % ROUT;
    int c  = (idx / (ROUT * ROUT)) % RC;
    int n  = idx / (ROUT * ROUT * RC);

    float im = (float)(*image_size_p);
    float scale_w = (float)RW / im;
    float scale_h = (float)RH / im;

    float bx = boxes[n * 4 + 0];
    float by = boxes[n * 4 + 1];
    float bw = boxes[n * 4 + 2];
    float bh = boxes[n * 4 + 3];
    bool bad = (bw <= 0.0f) || (bh <= 0.0f);

    float x1f = (bad ? 0.25f * im : bx) * scale_w;
    float x2f = (bad ? 0.75f * im : bx + bw) * scale_w;
    float y1f = (bad ? 0.25f * im : by) * scale_h;
    float y2f = (bad ? 0.75f * im : by + bh) * scale_h;

    // astype(int32) truncates toward zero — same as C cast.
    int x1 = max(0, (int)x1f);
    int y1 = max(0, (int)y1f);
    int x2 = min(RW, (int)x2f + 1);
    int y2 = min(RH, (int)y2f + 1);
    if (x2 <= x1 + 1) x2 = min(x1 + 2, RW);
    if (y2 <= y1 + 1) y2 = min(y1 + 2, RH);
    x1 = min(max(x1, 0), RW - 2);
    y1 = min(max(y1, 0), RH - 2);
    x2 = max(x1 + 1, min(x2, RW));
    y2 = max(y1 + 1, min(y2, RH));

    int szx = x2 - x1;
    int szy = y2 - y1;
    // bin k covers [lo + floor(k*sz/OUT), lo + ceil((k+1)*sz/OUT))
    int sx = x1 + (kx * szx) / ROUT;
    int ex = x1 + ((kx + 1) * szx + ROUT - 1) / ROUT;
    int sy = y1 + (ky * szy) / ROUT;
    int ey = y1 + ((ky + 1) * szy + ROUT - 1) / ROUT;

    const float* __restrict__ f = feat + c * (RH * RW);
    float m = -INFINITY;
    for (int y = sy; y < ey; ++y) {
        const float* __restrict__ row = f + y * RW;
        for (int x = sx; x < ex; ++x) {
            m = fmaxf(m, row[x]);
        }
    }
    out[idx] = m;
}

extern "C" void kernel_launch(void* const* d_in, const int* in_sizes, int n_in,
                              void* d_out, int out_size, void* d_ws, size_t ws_size,
                              hipStream_t stream) {
    const float* feat  = (const float*)d_in[0];
    const float* boxes = (const float*)d_in[1];
    const int* im_sz   = (const int*)d_in[2];
    float* out = (float*)d_out;

    const int total = RN * RC * ROUT * ROUT;
    const int block = 256;
    const int grid = (total + block - 1) / block;
    roi_pool_kernel<<<grid, block, 0, stream>>>(feat, boxes, im_sz, out);
}